// Round 8
// baseline (217.989 us; speedup 1.0000x reference)
//
#include <hip/hip_runtime.h>
#include <hip/hip_bf16.h>

// OneStep: out = W - c * K^T (K W - V),  c = 0.2/(CTX*D) = 9.5367431640625e-8
// W:(4096,4096) K:(512,4096) V:(512,4096) fp32 -> out (4096,4096) fp32.
// bf16 MFMA w/ fp32 acc => absmax 2.441e-4 = 1 bf16 ulp (threshold 1.69e-3).
//
// R7 post-mortem: hipLaunchCooperativeKernel never ran under graph capture
// (output stayed zero). Reverted to 3 launches. Cross-round accounting shows
// ~65 us fixed harness overhead in the timed window -> optimize kernels only.
// R8: (a) k2 with SWAPPED MFMA operands (A=Rt rows, B=Kt rows) so acc f32x4 =
// 4 consecutive out columns -> pure-register float4 epilogue, no LDS, no
// barriers; (b) k1 staging double-buffered (vmcnt(8) pipeline), still
// barrier-free.

typedef __bf16 bf16_t;
typedef __bf16 bf16x8 __attribute__((ext_vector_type(8)));
typedef float f32x4 __attribute__((ext_vector_type(4)));

#define D_DIM 4096
#define CTX_N 512
#define UPD_SCALE 9.5367431640625e-8f

__device__ __forceinline__ void gld16(const bf16_t* g, bf16_t* l) {
    __builtin_amdgcn_global_load_lds(
        (const __attribute__((address_space(1))) void*)g,
        (__attribute__((address_space(3))) void*)l, 16, 0, 0);
}

// ---- transpose+convert: src (M x N) fp32 -> dstT (N x M) bf16
//      [+ dstN (M x N) bf16].  64x64 tile; pad-65 LDS (2-way = free). ----
__device__ __forceinline__ void t_body2(
    float* tile, const float* __restrict__ src, bf16_t* __restrict__ dstT,
    bf16_t* __restrict__ dstN, int M, int N, int bx, int by)
{
    const int tid = threadIdx.x;
    const int C0 = bx * 64, R0 = by * 64;
    const int r  = tid >> 2, cs = (tid & 3) * 16;

    const float* s = src + (size_t)(R0 + r) * N + C0 + cs;
    float f[16];
#pragma unroll
    for (int u = 0; u < 4; ++u) {
        const float4 v = ((const float4*)s)[u];
        f[4 * u + 0] = v.x; f[4 * u + 1] = v.y; f[4 * u + 2] = v.z; f[4 * u + 3] = v.w;
    }
#pragma unroll
    for (int u = 0; u < 16; ++u) tile[r * 65 + cs + u] = f[u];

    if (dstN) {
        bf16x8 v0, v1;
#pragma unroll
        for (int u = 0; u < 8; ++u) { v0[u] = (bf16_t)f[u]; v1[u] = (bf16_t)f[8 + u]; }
        bf16_t* d = dstN + (size_t)(R0 + r) * N + C0 + cs;
        *(bf16x8*)d = v0; *(bf16x8*)(d + 8) = v1;
    }
    __syncthreads();

    bf16x8 o0, o1;
#pragma unroll
    for (int u = 0; u < 8; ++u) {
        o0[u] = (bf16_t)tile[(cs + u) * 65 + r];
        o1[u] = (bf16_t)tile[(cs + 8 + u) * 65 + r];
    }
    bf16_t* d = dstT + (size_t)(C0 + r) * M + R0 + cs;
    *(bf16x8*)d = o0; *(bf16x8*)(d + 8) = o1;
}

// One launch for all three transposes: y<64 -> W, 64..71 -> K(+Kb), 72..79 -> V
__global__ __launch_bounds__(256) void t_all(
    const float* __restrict__ W, const float* __restrict__ K,
    const float* __restrict__ V, bf16_t* __restrict__ Wt,
    bf16_t* __restrict__ Kt, bf16_t* __restrict__ Kb, bf16_t* __restrict__ Vt)
{
    __shared__ float tile[64 * 65];
    const int y = blockIdx.y;
    if (y < 64)      t_body2(tile, W, Wt, nullptr, D_DIM, D_DIM, blockIdx.x, y);
    else if (y < 72) t_body2(tile, K, Kt, Kb,      CTX_N, D_DIM, blockIdx.x, y - 64);
    else             t_body2(tile, V, Vt, nullptr, CTX_N, D_DIM, blockIdx.x, y - 72);
}

// MFMA 16x16x32 bf16 (m89/m91): A/B frag: idx=lane&15, k=quad*8+j (8 bf16);
// C/D: row(m)=quad*4+reg, col(n)=lane&15.  D[m][n] = sum_k A(m,k)*B(n,k).

// ---- K1: Rt[j][c] = sum_k Wt[j][k]*Kb[c][k] - Vt[j][c]  (4096 x 512) ----
// Barrier-free K-split + DOUBLE-BUFFERED wave-private staging: wave w owns
// k in [w*1024,(w+1)*1024); issue iter i+1 loads, vmcnt(8) waits iter i.
// grid (64 j, 8 c): id%8 = j%8 pins c-sharers of a Wt slice per XCD.
__global__ __launch_bounds__(256) void k1_residual(
    const bf16_t* __restrict__ Wt, const bf16_t* __restrict__ Kb,
    const bf16_t* __restrict__ Vt, bf16_t* __restrict__ Rt)
{
    __shared__ __align__(16) char smem[65536];  // 2 x (4 waves x (As+Bs))

    const int tid = threadIdx.x, wave = tid >> 6, lane = tid & 63;
    const int j0 = blockIdx.x * 64, c0 = blockIdx.y * 64;
    const int l15 = lane & 15, quad = lane >> 4;
    const int kw = wave * 1024;

    // buffer q (q=0,1): As at smem + q*32768 + wave*4096
    //                   Bs at smem + q*32768 + 16384 + wave*4096
    bf16_t* As[2] = {(bf16_t*)(smem + wave * 4096),
                     (bf16_t*)(smem + 32768 + wave * 4096)};
    bf16_t* Bs[2] = {(bf16_t*)(smem + 16384 + wave * 4096),
                     (bf16_t*)(smem + 32768 + 16384 + wave * 4096)};

    f32x4 acc[4][4] = {};

    const int srow = lane >> 2, sseg = (lane & 3) * 8;   // 16 rows / gld16 call
    const bf16_t* ga = Wt + (size_t)(j0 + srow) * D_DIM + kw + sseg;
    const bf16_t* gb = Kb + (size_t)(c0 + srow) * D_DIM + kw + sseg;

    // prologue: stage iter 0 into buf 0
#pragma unroll
    for (int c = 0; c < 4; ++c) {
        gld16(ga + (size_t)(c * 16) * D_DIM, As[0] + lane * 8 + c * 512);
        gld16(gb + (size_t)(c * 16) * D_DIM, Bs[0] + lane * 8 + c * 512);
    }

    for (int i = 0; i < 32; ++i) {
        const int cur = i & 1, nxt = cur ^ 1;
        if (i < 31) {
            const int ko = (i + 1) * 32;
#pragma unroll
            for (int c = 0; c < 4; ++c) {
                gld16(ga + ko + (size_t)(c * 16) * D_DIM, As[nxt] + lane * 8 + c * 512);
                gld16(gb + ko + (size_t)(c * 16) * D_DIM, Bs[nxt] + lane * 8 + c * 512);
            }
            __builtin_amdgcn_s_waitcnt(0x0f78);  // vmcnt(8): iter-i loads done
        } else {
            __builtin_amdgcn_s_waitcnt(0x0f70);  // vmcnt(0)
        }
        bf16x8 a[4], b[4];
#pragma unroll
        for (int mi = 0; mi < 4; ++mi)
            a[mi] = *(const bf16x8*)(As[cur] + (mi * 16 + l15) * 32 + quad * 8);
#pragma unroll
        for (int ni = 0; ni < 4; ++ni)
            b[ni] = *(const bf16x8*)(Bs[cur] + (ni * 16 + l15) * 32 + quad * 8);
#pragma unroll
        for (int mi = 0; mi < 4; ++mi)
#pragma unroll
            for (int ni = 0; ni < 4; ++ni)
                acc[mi][ni] = __builtin_amdgcn_mfma_f32_16x16x32_bf16(
                    a[mi], b[ni], acc[mi][ni], 0, 0, 0);
    }

    // Cross-wave reduction: ep[64][68] f32 (17.4 KB) aliases dead staging.
    float* ep = (float*)smem;
    __syncthreads();
#pragma unroll
    for (int w = 0; w < 4; ++w) {
        if (wave == w) {
#pragma unroll
            for (int mi = 0; mi < 4; ++mi)
#pragma unroll
                for (int ni = 0; ni < 4; ++ni)
#pragma unroll
                    for (int r = 0; r < 4; ++r) {
                        const int row = mi * 16 + quad * 4 + r;
                        const int col = ni * 16 + l15;
                        if (w == 0) ep[row * 68 + col]  = acc[mi][ni][r];
                        else        ep[row * 68 + col] += acc[mi][ni][r];
                    }
        }
        __syncthreads();
    }

    // Epilogue: Rt = ep - Vt, vectorized.
    {
        const int row = tid >> 2, cs = (tid & 3) * 16;
        const size_t rbase = (size_t)(j0 + row) * CTX_N + c0 + cs;
        float e[16];
#pragma unroll
        for (int u = 0; u < 4; ++u) {
            const float4 v = ((const float4*)(ep + row * 68 + cs))[u];
            e[4 * u + 0] = v.x; e[4 * u + 1] = v.y;
            e[4 * u + 2] = v.z; e[4 * u + 3] = v.w;
        }
        const bf16x8 v0 = *(const bf16x8*)(Vt + rbase);
        const bf16x8 v1 = *(const bf16x8*)(Vt + rbase + 8);
        bf16x8 o0, o1;
#pragma unroll
        for (int u = 0; u < 8; ++u) {
            o0[u] = (bf16_t)(e[u]     - (float)v0[u]);
            o1[u] = (bf16_t)(e[8 + u] - (float)v1[u]);
        }
        *(bf16x8*)(Rt + rbase)     = o0;
        *(bf16x8*)(Rt + rbase + 8) = o1;
    }
}

// ---- K2: out[i][j] = W[i][j] - c * sum_c Kt[i][c]*Rt[j][c]  (4096x4096) ----
// 128x128 tile, BK=32, 4 waves of 64x64. SWAPPED operands: A=Rt row (m=j),
// B=Kt row (n=i) -> acc[mj][nj] reg r is out[i][jbase+r]: register-only
// float4 epilogue (W load + out store at identical addresses), no ep LDS.
__global__ __launch_bounds__(256) void k2_update(
    const bf16_t* __restrict__ Kt, const bf16_t* __restrict__ Rt,
    const float* __restrict__ W, float* __restrict__ out)
{
    __shared__ __align__(16) bf16_t As[128 * 32];  // Kt rows (i,c) 8 KB
    __shared__ __align__(16) bf16_t Bs[128 * 32];  // Rt rows (j,c) 8 KB

    const int tid = threadIdx.x;
    const int j0 = blockIdx.x * 128, i0 = blockIdx.y * 128;
    const int lane = tid & 63, wave = tid >> 6;
    const int wi = (wave >> 1) * 64, wj = (wave & 1) * 64;
    const int l15 = lane & 15, quad = lane >> 4;

    f32x4 acc[4][4] = {};  // [mj][nj]: m=j-dir, n=i-dir

    const bf16_t* ga = Kt + (size_t)(i0 + (tid >> 2)) * CTX_N + (tid & 3) * 8;
    const bf16_t* gb = Rt + (size_t)(j0 + (tid >> 2)) * CTX_N + (tid & 3) * 8;
    bf16_t* la = (bf16_t*)((char*)As + tid * 16);
    bf16_t* lb = (bf16_t*)((char*)Bs + tid * 16);

    for (int cc = 0; cc < CTX_N; cc += 32) {
        gld16(ga + cc, la);
        gld16(ga + cc + (size_t)64 * CTX_N, la + 64 * 32);
        gld16(gb + cc, lb);
        gld16(gb + cc + (size_t)64 * CTX_N, lb + 64 * 32);
        __syncthreads();
        bf16x8 aI[4], bJ[4];
#pragma unroll
        for (int ni = 0; ni < 4; ++ni)   // i-rows (B operand)
            aI[ni] = *(const bf16x8*)(As + (wi + ni * 16 + l15) * 32 + quad * 8);
#pragma unroll
        for (int mj = 0; mj < 4; ++mj)   // j-rows (A operand)
            bJ[mj] = *(const bf16x8*)(Bs + (wj + mj * 16 + l15) * 32 + quad * 8);
#pragma unroll
        for (int mj = 0; mj < 4; ++mj)
#pragma unroll
            for (int ni = 0; ni < 4; ++ni)
                acc[mj][ni] = __builtin_amdgcn_mfma_f32_16x16x32_bf16(
                    bJ[mj], aI[ni], acc[mj][ni], 0, 0, 0);
        __syncthreads();
    }

    // Register epilogue: i = i0+wi+ni*16+l15 (lane-fixed rows),
    // j = j0+wj+mj*16+quad*4 (+r in the float4).
#pragma unroll
    for (int mj = 0; mj < 4; ++mj) {
        const int jb = j0 + wj + mj * 16 + quad * 4;
        float4 wv[4];
#pragma unroll
        for (int ni = 0; ni < 4; ++ni) {
            const size_t idx = (size_t)(i0 + wi + ni * 16 + l15) * D_DIM + jb;
            wv[ni] = *(const float4*)(W + idx);
        }
#pragma unroll
        for (int ni = 0; ni < 4; ++ni) {
            const size_t idx = (size_t)(i0 + wi + ni * 16 + l15) * D_DIM + jb;
            float4 ov;
            ov.x = wv[ni].x - UPD_SCALE * acc[mj][ni][0];
            ov.y = wv[ni].y - UPD_SCALE * acc[mj][ni][1];
            ov.z = wv[ni].z - UPD_SCALE * acc[mj][ni][2];
            ov.w = wv[ni].w - UPD_SCALE * acc[mj][ni][3];
            *(float4*)(out + idx) = ov;
        }
    }
}

extern "C" void kernel_launch(void* const* d_in, const int* in_sizes, int n_in,
                              void* d_out, int out_size, void* d_ws, size_t ws_size,
                              hipStream_t stream) {
    const float* W = (const float*)d_in[0];   // (4096, 4096)
    const float* K = (const float*)d_in[1];   // (512, 4096)
    const float* V = (const float*)d_in[2];   // (512, 4096)
    float* out = (float*)d_out;

    char* ws = (char*)d_ws;                    // 48 MB used
    bf16_t* Wt = (bf16_t*)(ws);                            // (4096,4096) W^T
    bf16_t* Kt = (bf16_t*)(ws + (size_t)32 * 1024 * 1024); // (4096,512) K^T
    bf16_t* Kb = (bf16_t*)(ws + (size_t)36 * 1024 * 1024); // (512,4096) K
    bf16_t* Vt = (bf16_t*)(ws + (size_t)40 * 1024 * 1024); // (4096,512) V^T
    bf16_t* Rt = (bf16_t*)(ws + (size_t)44 * 1024 * 1024); // (4096,512) R^T

    t_all      <<<dim3(64, 80), 256, 0, stream>>>(W, K, V, Wt, Kt, Kb, Vt);
    k1_residual<<<dim3(64, 8),  256, 0, stream>>>(Wt, Kb, Vt, Rt);
    k2_update  <<<dim3(32, 32), 256, 0, stream>>>(Kt, Rt, W, out);
}